// Round 1
// baseline (405.926 us; speedup 1.0000x reference)
//
#include <hip/hip_runtime.h>

// Chamfer NN squared distance, both directions.
// B=8, N=M=16384, D=3 (fixed by the reference problem).
//
// dist(x_i) = |x_i|^2 + min_j (|y_j|^2 - 2 x_i . y_j)
// y staged in LDS as float4 {y0,y1,y2,|y|^2}; -2*x precomputed per thread.
// Per pair: 3 FMA + amortized min3.

#define NB        8
#define NPTS      16384
#define TILE      2048      // y points per LDS tile (32 KB of float4)
#define THREADS   256
#define PPT       2         // query points per thread
#define PTS_PER_BLOCK (THREADS * PPT)   // 512

__global__ __launch_bounds__(THREADS, 2)
void nnd_kernel(const float* __restrict__ x1,
                const float* __restrict__ x2,
                float* __restrict__ out)
{
    constexpr int blocks_per_dir = (NB * NPTS) / PTS_PER_BLOCK; // 256
    constexpr int chunks_per_batch = NPTS / PTS_PER_BLOCK;      // 32

    const int bid   = blockIdx.x;
    const int dir   = bid / blocks_per_dir;          // 0: x1->x2, 1: x2->x1
    const int rem   = bid % blocks_per_dir;
    const int batch = rem / chunks_per_batch;
    const int chunk = rem % chunks_per_batch;

    const float* __restrict__ xq = (dir == 0) ? x1 : x2;
    const float* __restrict__ yr = (dir == 0) ? x2 : x1;
    const float* __restrict__ xb = xq + (size_t)batch * NPTS * 3;
    const float* __restrict__ yb = yr + (size_t)batch * NPTS * 3;
    float* __restrict__ ob = out + (size_t)dir * NB * NPTS
                                 + (size_t)batch * NPTS
                                 + (size_t)chunk * PTS_PER_BLOCK;

    __shared__ float4 ytile[TILE];

    const int t  = threadIdx.x;
    const int i0 = chunk * PTS_PER_BLOCK + t;
    const int i1 = i0 + THREADS;

    // Load the two query points, precompute -2*x and |x|^2.
    const float ax = xb[3 * i0 + 0], ay = xb[3 * i0 + 1], az = xb[3 * i0 + 2];
    const float bx = xb[3 * i1 + 0], by = xb[3 * i1 + 1], bz = xb[3 * i1 + 2];
    const float sa = ax * ax + ay * ay + az * az;
    const float sb = bx * bx + by * by + bz * bz;
    const float nax = -2.0f * ax, nay = -2.0f * ay, naz = -2.0f * az;
    const float nbx = -2.0f * bx, nby = -2.0f * by, nbz = -2.0f * bz;

    float mA0 = INFINITY, mA1 = INFINITY;
    float mB0 = INFINITY, mB1 = INFINITY;

    for (int tile0 = 0; tile0 < NPTS; tile0 += TILE) {
        // Stage TILE y points into LDS (coalesced-ish 12B/lane reads; cost
        // is amortized 512x by the inner loop).
        for (int k = t; k < TILE; k += THREADS) {
            const float* yp = yb + 3 * (size_t)(tile0 + k);
            const float a = yp[0], b = yp[1], c = yp[2];
            ytile[k] = make_float4(a, b, c, a * a + b * b + c * c);
        }
        __syncthreads();

#pragma unroll 2
        for (int j = 0; j < TILE; j += 4) {
            const float4 p0 = ytile[j + 0];
            const float4 p1 = ytile[j + 1];
            const float4 p2 = ytile[j + 2];
            const float4 p3 = ytile[j + 3];

            const float dA0 = fmaf(nax, p0.x, fmaf(nay, p0.y, fmaf(naz, p0.z, p0.w)));
            const float dA1 = fmaf(nax, p1.x, fmaf(nay, p1.y, fmaf(naz, p1.z, p1.w)));
            const float dA2 = fmaf(nax, p2.x, fmaf(nay, p2.y, fmaf(naz, p2.z, p2.w)));
            const float dA3 = fmaf(nax, p3.x, fmaf(nay, p3.y, fmaf(naz, p3.z, p3.w)));

            const float dB0 = fmaf(nbx, p0.x, fmaf(nby, p0.y, fmaf(nbz, p0.z, p0.w)));
            const float dB1 = fmaf(nbx, p1.x, fmaf(nby, p1.y, fmaf(nbz, p1.z, p1.w)));
            const float dB2 = fmaf(nbx, p2.x, fmaf(nby, p2.y, fmaf(nbz, p2.z, p2.w)));
            const float dB3 = fmaf(nbx, p3.x, fmaf(nby, p3.y, fmaf(nbz, p3.z, p3.w)));

            // fminf(fminf(a,b),c) -> v_min3_f32; two independent chains per point.
            mA0 = fminf(fminf(dA0, dA1), mA0);
            mA1 = fminf(fminf(dA2, dA3), mA1);
            mB0 = fminf(fminf(dB0, dB1), mB0);
            mB1 = fminf(fminf(dB2, dB3), mB1);
        }
        __syncthreads();
    }

    ob[t]           = sa + fminf(mA0, mA1);
    ob[t + THREADS] = sb + fminf(mB0, mB1);
}

extern "C" void kernel_launch(void* const* d_in, const int* in_sizes, int n_in,
                              void* d_out, int out_size, void* d_ws, size_t ws_size,
                              hipStream_t stream) {
    const float* x1 = (const float*)d_in[0];
    const float* x2 = (const float*)d_in[1];
    float* out = (float*)d_out;

    const int total_blocks = 2 * (NB * NPTS) / PTS_PER_BLOCK; // 512
    nnd_kernel<<<dim3(total_blocks), dim3(THREADS), 0, stream>>>(x1, x2, out);
}

// Round 2
// 359.908 us; speedup vs baseline: 1.1279x; 1.1279x over previous
//
#include <hip/hip_runtime.h>

// Chamfer NN squared distance, both directions. B=8, N=M=16384, D=3, fp32.
//
// dist(x_i) = |x_i|^2 + min_j (|y_j|^2 - 2 x_i . y_j)
// y staged in LDS as SoA {x,y,z,|y|^2}; -2*x splatted into v2f per thread.
// Inner op: v_pk_fma_f32 (2 y-points per instruction) + v_min3_f32.
// y-range split 4-ways across blocks -> grid 1024 (4 blocks/CU); partial
// minima merged with atomicMin on uint bits (distances clamped >= 0, so
// IEEE-754 bit pattern ordering == float ordering). Out pre-init to 0xFF.

#define NB      8
#define NPTS    16384
#define THREADS 256
#define PPT     4                       // query points per thread
#define QPB     (THREADS * PPT)         // 1024 query points per block
#define TILE    2048                    // y points per LDS tile
#define NSEG    4                       // y-range segments (grid multiplier)
#define YSEG    (NPTS / NSEG)           // 4096

typedef float v2f __attribute__((ext_vector_type(2)));

__device__ __forceinline__ v2f pk_fma(v2f a, v2f b, v2f c) {
    v2f d;
    asm("v_pk_fma_f32 %0, %1, %2, %3" : "=v"(d) : "v"(a), "v"(b), "v"(c));
    return d;
}

__device__ __forceinline__ float min3f(float a, float b, float c) {
    float d;
    asm("v_min3_f32 %0, %1, %2, %3" : "=v"(d) : "v"(a), "v"(b), "v"(c));
    return d;
}

__global__ __launch_bounds__(THREADS, 4)
void nnd_kernel(const float* __restrict__ x1,
                const float* __restrict__ x2,
                float* __restrict__ out)
{
    // bid = ((dir*NB + batch)*chunks + chunk)*NSEG + yseg
    constexpr int chunks = NPTS / QPB;  // 16
    const int bid   = blockIdx.x;
    const int yseg  = bid % NSEG;
    const int rem1  = bid / NSEG;
    const int chunk = rem1 % chunks;
    const int rem2  = rem1 / chunks;
    const int batch = rem2 % NB;
    const int dir   = rem2 / NB;

    const float* __restrict__ xq = (dir == 0) ? x1 : x2;
    const float* __restrict__ yr = (dir == 0) ? x2 : x1;
    const float* __restrict__ xb = xq + (size_t)batch * NPTS * 3;
    const float* __restrict__ yb = yr + (size_t)batch * NPTS * 3;
    float* __restrict__ ob = out + (size_t)dir * NB * NPTS
                                 + (size_t)batch * NPTS
                                 + (size_t)chunk * QPB;

    __shared__ __align__(16) float ysx[TILE];
    __shared__ __align__(16) float ysy[TILE];
    __shared__ __align__(16) float ysz[TILE];
    __shared__ __align__(16) float ysw[TILE];

    const int t = threadIdx.x;

    // Load PPT query points; precompute -2x splats and |x|^2.
    v2f nx[PPT], ny[PPT], nz[PPT];
    float sx[PPT];
    float a0[PPT], a1[PPT];
#pragma unroll
    for (int p = 0; p < PPT; ++p) {
        const int q = chunk * QPB + t + p * THREADS;
        const float qx = xb[3 * q + 0], qy = xb[3 * q + 1], qz = xb[3 * q + 2];
        sx[p] = qx * qx + qy * qy + qz * qz;
        const float mx = -2.0f * qx, my = -2.0f * qy, mz = -2.0f * qz;
        nx[p] = (v2f){mx, mx};
        ny[p] = (v2f){my, my};
        nz[p] = (v2f){mz, mz};
        a0[p] = INFINITY;
        a1[p] = INFINITY;
    }

    const int segbase = yseg * YSEG;

    for (int tile0 = 0; tile0 < YSEG; tile0 += TILE) {
        // Stage TILE y points into SoA LDS.
        for (int k = t; k < TILE; k += THREADS) {
            const float* yp = yb + 3 * (size_t)(segbase + tile0 + k);
            const float a = yp[0], b = yp[1], c = yp[2];
            ysx[k] = a; ysy[k] = b; ysz[k] = c;
            ysw[k] = a * a + b * b + c * c;
        }
        __syncthreads();

#pragma unroll 2
        for (int j = 0; j < TILE; j += 4) {
            const v2f x01 = *(const v2f*)&ysx[j];
            const v2f x23 = *(const v2f*)&ysx[j + 2];
            const v2f y01 = *(const v2f*)&ysy[j];
            const v2f y23 = *(const v2f*)&ysy[j + 2];
            const v2f z01 = *(const v2f*)&ysz[j];
            const v2f z23 = *(const v2f*)&ysz[j + 2];
            const v2f w01 = *(const v2f*)&ysw[j];
            const v2f w23 = *(const v2f*)&ysw[j + 2];

#pragma unroll
            for (int p = 0; p < PPT; ++p) {
                v2f t01 = pk_fma(nz[p], z01, w01);
                t01 = pk_fma(ny[p], y01, t01);
                t01 = pk_fma(nx[p], x01, t01);
                v2f t23 = pk_fma(nz[p], z23, w23);
                t23 = pk_fma(ny[p], y23, t23);
                t23 = pk_fma(nx[p], x23, t23);
                a0[p] = min3f(t01.x, t01.y, a0[p]);
                a1[p] = min3f(t23.x, t23.y, a1[p]);
            }
        }
        __syncthreads();
    }

#pragma unroll
    for (int p = 0; p < PPT; ++p) {
        float d = sx[p] + fminf(a0[p], a1[p]);
        d = fmaxf(d, 0.0f);  // distances are >=0 up to rounding; keeps uint-min valid
        atomicMin((unsigned int*)&ob[t + p * THREADS], __float_as_uint(d));
    }
}

extern "C" void kernel_launch(void* const* d_in, const int* in_sizes, int n_in,
                              void* d_out, int out_size, void* d_ws, size_t ws_size,
                              hipStream_t stream) {
    const float* x1 = (const float*)d_in[0];
    const float* x2 = (const float*)d_in[1];
    float* out = (float*)d_out;

    // Init out to 0xFFFFFFFF (uint max) so atomicMin works from a clean slate.
    hipMemsetAsync(out, 0xFF, (size_t)out_size * sizeof(float), stream);

    constexpr int total_blocks = 2 * NB * (NPTS / QPB) * NSEG; // 1024
    nnd_kernel<<<dim3(total_blocks), dim3(THREADS), 0, stream>>>(x1, x2, out);
}